// Round 2
// baseline (384.012 us; speedup 1.0000x reference)
//
#include <hip/hip_runtime.h>
#include <stdint.h>

#define NEG (-100.0f)

#define NE 300      // embedding dim
#define NB 64       // batch
#define NL 512      // seq len
#define NP 200      // patterns
#define ND 2800     // diag rows = P*2*M
#define NH 100      // mlp hidden

#define KP 320      // padded K (300 emb + 1 bias-col + zeros)
#define UNITS 40    // 16B units per row (KP*2/16)
#define ROWB 640    // bytes per row

#define PT 8        // patterns per tile
#define DT 112      // diag rows per tile (PT*14)
#define NTILE 25    // pattern tiles (200/8)
#define LC 32       // l-chunk
#define NCHUNK 16   // 512/32

#define LDS_B   (DT*ROWB)          // 71680
#define LDS_A   (LC*ROWB)          // 20480
#define LDS_SC  (LC*DT*4)          // 14336
#define LDS_TOTAL (LDS_B + 2*LDS_A + 2*LDS_SC)   // 141312

using f32x4  = __attribute__((ext_vector_type(4))) float;
using bf16x8 = __attribute__((ext_vector_type(8))) __bf16;

static __device__ __forceinline__ uint16_t f2bf(float f) {
    union { float f; uint32_t u; } v; v.f = f;
    return (uint16_t)((v.u + 0x7FFFu + ((v.u >> 16) & 1u)) >> 16);   // RNE
}

// lane i gets lane i-1's value (within rows of 16); row-lane 0 gets 0.
static __device__ __forceinline__ float dpp_shr1(float x) {
    int r = __builtin_amdgcn_update_dpp(0, __float_as_int(x), 0x111, 0xF, 0xF, true);
    return __int_as_float(r);
}

// ---------------------------------------------------------------------------
// prep: gather emb rows by docs, convert to bf16, pad K to 320 (col 300 = 1.0
// for A / bias[d] for B), and store 16B units PRE-SWIZZLED (unit j stored at
// j ^ (row&7)) so the GEMM kernel can stage linearly and read swizzled.
// ---------------------------------------------------------------------------
__global__ void prep_kernel(const int* __restrict__ docs,
                            const float* __restrict__ emb,
                            const float* __restrict__ diags,
                            const float* __restrict__ bias,
                            uint16_t* __restrict__ A_ws,
                            uint16_t* __restrict__ B_ws)
{
    int tid = blockIdx.x * blockDim.x + threadIdx.x;
    const int totalA = NB * NL * UNITS;
    const int total  = totalA + ND * UNITS;
    if (tid >= total) return;
    const float* src; uint16_t* dst; float extra; int r, j;
    if (tid < totalA) {
        r = tid / UNITS; j = tid - r * UNITS;
        src = emb + (size_t)docs[r] * NE;
        dst = A_ws + (size_t)r * KP;
        extra = 1.0f;                       // bias column multiplier
    } else {
        int t2 = tid - totalA;
        r = t2 / UNITS; j = t2 - r * UNITS;
        src = diags + (size_t)r * NE;
        dst = B_ws + (size_t)r * KP;
        extra = bias[r];
    }
    int jp = j ^ (r & 7);                   // pre-swizzle 16B unit
    int e0 = j * 8;
    union { uint16_t h[8]; uint4 v; } u;
#pragma unroll
    for (int t = 0; t < 8; ++t) {
        int e = e0 + t;
        float f = (e < NE) ? src[e] : ((e == NE) ? extra : 0.0f);
        u.h[t] = f2bf(f);
    }
    *reinterpret_cast<uint4*>(dst + (size_t)jp * 8) = u.v;
}

// ---------------------------------------------------------------------------
// fused GEMM (bf16 MFMA 16x16x32) + max-plus scan.
// 8 waves: 0-3 MFMA (2x2 over 32 rows x 112 cols), 4 scan, 5-7 A staging.
// ---------------------------------------------------------------------------
template<int NFR>
static __device__ __forceinline__ void mfma_body(const char* __restrict__ Ab,
    const char* __restrict__ Bl, float* __restrict__ scw,
    int abase, int aswz, int cb, int rlo, int kq, int wr)
{
    f32x4 acc[NFR];
#pragma unroll
    for (int f = 0; f < NFR; ++f) acc[f] = f32x4{0.f, 0.f, 0.f, 0.f};
#pragma unroll
    for (int kk = 0; kk < KP / 32; ++kk) {
        int ab = abase + kk * 64 + kq * 16;
        bf16x8 av = *reinterpret_cast<const bf16x8*>(Ab + (ab ^ aswz));
#pragma unroll
        for (int f = 0; f < NFR; ++f) {
            int col = (cb + f) * 16 + rlo;
            int bby = (col * ROWB + kk * 64 + kq * 16) ^ ((col & 7) << 4);
            bf16x8 bv = *reinterpret_cast<const bf16x8*>(Bl + bby);
            acc[f] = __builtin_amdgcn_mfma_f32_16x16x32_bf16(av, bv, acc[f], 0, 0, 0);
        }
    }
    const int crow = wr * 16 + kq * 4;      // C/D: col=lane&15, row=(lane>>4)*4+reg
#pragma unroll
    for (int f = 0; f < NFR; ++f) {
        int col = (cb + f) * 16 + rlo;
#pragma unroll
        for (int rr = 0; rr < 4; ++rr)
            scw[(crow + rr) * DT + col] = acc[f][rr];
    }
}

static __device__ __forceinline__ void scan_chunk(const float* __restrict__ sc,
        float& h, float& s, float eps_r, bool is_m0, int i0, int i1)
{
    float xa = sc[i0], xb = sc[i1];
    for (int l = 0; l < LC; ++l) {
        float xa_n = 0.f, xb_n = 0.f;
        if (l + 1 < LC) {                       // prefetch next step's x
            xa_n = sc[(l + 1) * DT + i0];
            xb_n = sc[(l + 1) * DT + i1];
        }
        float hm1  = dpp_shr1(h);               // h[m-1]
        float t    = is_m0 ? NEG : (hm1 + eps_r);
        float ae   = fmaxf(h, t);               // after_eps[m]
        float aem1 = dpp_shr1(ae);              // after_eps[m-1]
        float mn   = is_m0 ? 0.0f : (aem1 + xb);// main[m] (restart at m=0)
        h = fmaxf(mn, ae + xa);                 // max(main, self_loop)
        s = fmaxf(s, h);                        // only lane m==6 meaningful
        xa = xa_n; xb = xb_n;
    }
}

__global__ __launch_bounds__(512, 1)
void sopa_kernel(const uint16_t* __restrict__ A_ws,
                 const uint16_t* __restrict__ B_ws,
                 const float* __restrict__ epsilon,
                 float* __restrict__ scores_g)
{
    extern __shared__ char smem[];
    // LDS layout: [B tile | A buf0 | A buf1 | SC buf0 | SC buf1]
    char* Bl = smem;

    const int blk = blockIdx.x;
    const int bb  = blk / NTILE;
    const int pt  = blk - bb * NTILE;
    const int d0  = pt * DT;
    const int p0  = pt * PT;

    const int tid  = threadIdx.x;
    const int wave = tid >> 6;
    const int lane = tid & 63;

    // prologue: stage full B tile (reused all 16 chunks) + A chunk 0
    {
        const uint4* s4 = (const uint4*)(B_ws + (size_t)d0 * KP);
        uint4* d4 = (uint4*)Bl;
        for (int u = tid; u < LDS_B / 16; u += 512) d4[u] = s4[u];
        const uint4* a4 = (const uint4*)(A_ws + (size_t)(bb * NL) * KP);
        uint4* ad = (uint4*)(smem + LDS_B);
        for (int u = tid; u < LDS_A / 16; u += 512) ad[u] = a4[u];
    }
    __syncthreads();

    // MFMA-wave precompute (waves 0-3)
    const int rlo = lane & 15;
    const int kq  = lane >> 4;
    const int wr  = wave & 1;
    const int wc  = wave >> 1;
    const int cb  = wc * 4;                 // col-frag base: {0..3} or {4..6}
    const int arow  = wr * 16 + rlo;
    const int abase = arow * ROWB;
    const int aswz  = (arow & 7) << 4;

    // scan-wave state (wave 4): lane = p_local*8 + m  (m==7 lanes are dummies)
    const int  pp = lane >> 3;
    const int  mm = lane & 7;
    const bool is_m0 = (mm == 0);
    float eps_r = 0.0f;
    if (mm >= 1 && mm <= 6) eps_r = epsilon[(p0 + pp) * 6 + (mm - 1)];
    const int i0 = pp * 14 + mm;                       // x[p][0][m]
    const int i1 = pp * 14 + 7 + (mm ? mm - 1 : 0);    // x[p][1][m-1]
    float h = is_m0 ? 0.0f : NEG;
    float s = NEG;

    for (int c = 0; c < NCHUNK; ++c) {
        if (wave < 4) {
            const char* Ab  = smem + LDS_B + (c & 1) * LDS_A;
            float*      scw = (float*)(smem + LDS_B + 2 * LDS_A + (c & 1) * LDS_SC);
            if (wc == 0) mfma_body<4>(Ab, Bl, scw, abase, aswz, cb, rlo, kq, wr);
            else         mfma_body<3>(Ab, Bl, scw, abase, aswz, cb, rlo, kq, wr);
        } else if (wave == 4) {
            if (c > 0) {
                const float* scr = (const float*)(smem + LDS_B + 2 * LDS_A + ((c - 1) & 1) * LDS_SC);
                scan_chunk(scr, h, s, eps_r, is_m0, i0, i1);
            }
        } else {
            if (c + 1 < NCHUNK) {
                const uint4* s4 = (const uint4*)(A_ws + (size_t)(bb * NL + (c + 1) * LC) * KP);
                uint4* d4 = (uint4*)(smem + LDS_B + ((c + 1) & 1) * LDS_A);
                for (int u = tid - 320; u < LDS_A / 16; u += 192) d4[u] = s4[u];
            }
        }
        __syncthreads();
    }

    if (wave == 4) {
        const float* scr = (const float*)(smem + LDS_B + 2 * LDS_A + ((NCHUNK - 1) & 1) * LDS_SC);
        scan_chunk(scr, h, s, eps_r, is_m0, i0, i1);
        if (mm == 6) scores_g[bb * NP + p0 + pp] = s;
    }
}

// ---------------------------------------------------------------------------
// tiny MLP head: one block per batch row, fp32
// ---------------------------------------------------------------------------
__global__ void mlp_kernel(const float* __restrict__ scores_g,
                           const float* __restrict__ w1, const float* __restrict__ b1,
                           const float* __restrict__ w2, const float* __restrict__ b2,
                           const float* __restrict__ w3, const float* __restrict__ b3,
                           float* __restrict__ out)
{
    __shared__ float sc[NP];
    __shared__ float h1[NH];
    __shared__ float h2[NH];
    int b = blockIdx.x, t = threadIdx.x;
    for (int i = t; i < NP; i += blockDim.x) sc[i] = scores_g[b * NP + i];
    __syncthreads();
    if (t < NH) {
        float acc = b1[t];
        for (int k = 0; k < NP; ++k) acc += sc[k] * w1[k * NH + t];
        h1[t] = fmaxf(acc, 0.0f);
    }
    __syncthreads();
    if (t < NH) {
        float acc = b2[t];
        for (int k = 0; k < NH; ++k) acc += h1[k] * w2[k * NH + t];
        h2[t] = fmaxf(acc, 0.0f);
    }
    __syncthreads();
    if (t == 0) {
        float l0 = b3[0], l1 = b3[1];
        for (int k = 0; k < NH; ++k) { l0 += h2[k] * w3[k * 2]; l1 += h2[k] * w3[k * 2 + 1]; }
        float mx  = fmaxf(l0, l1);
        float lse = mx + logf(expf(l0 - mx) + expf(l1 - mx));
        out[b * 2 + 0] = l0 - lse;
        out[b * 2 + 1] = l1 - lse;
    }
}

extern "C" void kernel_launch(void* const* d_in, const int* in_sizes, int n_in,
                              void* d_out, int out_size, void* d_ws, size_t ws_size,
                              hipStream_t stream)
{
    const int*   docs  = (const int*)  d_in[0];
    const float* emb   = (const float*)d_in[1];
    const float* diags = (const float*)d_in[2];
    const float* bias  = (const float*)d_in[3];
    const float* eps   = (const float*)d_in[4];
    const float* w1 = (const float*)d_in[5];
    const float* b1 = (const float*)d_in[6];
    const float* w2 = (const float*)d_in[7];
    const float* b2 = (const float*)d_in[8];
    const float* w3 = (const float*)d_in[9];
    const float* b3 = (const float*)d_in[10];
    float* out = (float*)d_out;

    char* ws = (char*)d_ws;
    uint16_t* A_ws     = (uint16_t*)ws;                              // 20,971,520 B
    uint16_t* B_ws     = (uint16_t*)(ws + 20971520);                 //  1,792,000 B
    float*    scores_g = (float*)   (ws + 20971520 + 1792000);       //     51,200 B

    {
        int totalUnits = (NB * NL + ND) * UNITS;
        int blocks = (totalUnits + 255) / 256;
        prep_kernel<<<blocks, 256, 0, stream>>>(docs, emb, diags, bias, A_ws, B_ws);
    }

    (void)hipFuncSetAttribute(reinterpret_cast<const void*>(sopa_kernel),
                              hipFuncAttributeMaxDynamicSharedMemorySize, LDS_TOTAL);
    sopa_kernel<<<NB * NTILE, 512, LDS_TOTAL, stream>>>(A_ws, B_ws, eps, scores_g);

    mlp_kernel<<<NB, 128, 0, stream>>>(scores_g, w1, b1, w2, b2, w3, b3, out);
}

// Round 3
// 378.082 us; speedup vs baseline: 1.0157x; 1.0157x over previous
//
#include <hip/hip_runtime.h>
#include <stdint.h>

#define NEG (-100.0f)

#define NE 300      // embedding dim
#define NB 64       // batch
#define NL 512      // seq len
#define NP 200      // patterns
#define ND 2800     // diag rows = P*2*M
#define NH 100      // mlp hidden

#define KP 320      // padded K (300 emb + 1 bias-col + zeros)
#define UNITS 40    // 16B units per row (KP*2/16)
#define ROWB 640    // bytes per row

#define PT 8        // patterns per tile
#define DT 112      // diag rows per tile (PT*14)
#define NTILE 25    // pattern tiles (200/8)
#define LC 32       // l-chunk
#define NCHUNK 16   // 512/32
#define SCP 113     // padded score-tile stride in floats (kills write conflicts)

#define LDS_A   (LC*ROWB)          // 20480
#define LDS_SC  (LC*SCP*4)         // 14464
#define LDS_TOTAL (2*LDS_A + 2*LDS_SC)   // 69888

using f32x4  = __attribute__((ext_vector_type(4))) float;
using bf16x8 = __attribute__((ext_vector_type(8))) __bf16;

static __device__ __forceinline__ uint16_t f2bf(float f) {
    union { float f; uint32_t u; } v; v.f = f;
    return (uint16_t)((v.u + 0x7FFFu + ((v.u >> 16) & 1u)) >> 16);   // RNE
}

// lane i gets lane i-1's value (within rows of 16); row-lane 0 gets 0.
static __device__ __forceinline__ float dpp_shr1(float x) {
    int r = __builtin_amdgcn_update_dpp(0, __float_as_int(x), 0x111, 0xF, 0xF, true);
    return __int_as_float(r);
}

// ---------------------------------------------------------------------------
// prep: gather emb rows by docs, convert to bf16, pad K to 320 (col 300 = 1.0
// for A / bias[d] for B), and store 16B units PRE-SWIZZLED (unit j stored at
// j ^ (row&7)). A is read via linear LDS staging + swizzled ds_read; B is
// read straight to registers with the XOR applied in the global address.
// ---------------------------------------------------------------------------
__global__ void prep_kernel(const int* __restrict__ docs,
                            const float* __restrict__ emb,
                            const float* __restrict__ diags,
                            const float* __restrict__ bias,
                            uint16_t* __restrict__ A_ws,
                            uint16_t* __restrict__ B_ws)
{
    int tid = blockIdx.x * blockDim.x + threadIdx.x;
    const int totalA = NB * NL * UNITS;
    const int total  = totalA + ND * UNITS;
    if (tid >= total) return;
    const float* src; uint16_t* dst; float extra; int r, j;
    if (tid < totalA) {
        r = tid / UNITS; j = tid - r * UNITS;
        src = emb + (size_t)docs[r] * NE;
        dst = A_ws + (size_t)r * KP;
        extra = 1.0f;                       // bias column multiplier
    } else {
        int t2 = tid - totalA;
        r = t2 / UNITS; j = t2 - r * UNITS;
        src = diags + (size_t)r * NE;
        dst = B_ws + (size_t)r * KP;
        extra = bias[r];
    }
    int jp = j ^ (r & 7);                   // pre-swizzle 16B unit
    int e0 = j * 8;
    union { uint16_t h[8]; uint4 v; } u;
#pragma unroll
    for (int t = 0; t < 8; ++t) {
        int e = e0 + t;
        float f = (e < NE) ? src[e] : ((e == NE) ? extra : 0.0f);
        u.h[t] = f2bf(f);
    }
    *reinterpret_cast<uint4*>(dst + (size_t)jp * 8) = u.v;
}

// ---------------------------------------------------------------------------
// fused GEMM (bf16 MFMA 16x16x32, B held in registers) + max-plus scan.
// 8 waves: 0-3 MFMA (2x2 wave grid over 32 rows x 112 cols), 4 scan,
// 5-7 A staging (double-buffered).
// ---------------------------------------------------------------------------
template<int NFR>
static __device__ __forceinline__ void mfma_body(const char* __restrict__ Ab,
    const bf16x8 (&breg)[4][10], float* __restrict__ scw,
    int abase, int aswz, int cb, int rlo, int kq, int wr)
{
    f32x4 acc[NFR];
#pragma unroll
    for (int f = 0; f < NFR; ++f) acc[f] = f32x4{0.f, 0.f, 0.f, 0.f};
#pragma unroll
    for (int kk = 0; kk < KP / 32; ++kk) {
        int ab = abase + kk * 64 + kq * 16;
        bf16x8 av = *reinterpret_cast<const bf16x8*>(Ab + (ab ^ aswz));
#pragma unroll
        for (int f = 0; f < NFR; ++f)
            acc[f] = __builtin_amdgcn_mfma_f32_16x16x32_bf16(av, breg[f][kk], acc[f], 0, 0, 0);
    }
    const int crow = wr * 16 + kq * 4;      // C/D: col=lane&15, row=(lane>>4)*4+reg
#pragma unroll
    for (int f = 0; f < NFR; ++f) {
        int col = (cb + f) * 16 + rlo;
#pragma unroll
        for (int rr = 0; rr < 4; ++rr)
            scw[(crow + rr) * SCP + col] = acc[f][rr];
    }
}

static __device__ __forceinline__ void scan_chunk(const float* __restrict__ sc,
        float& h, float& s, float eps_r, bool is_m0, int i0, int i1)
{
    float xa = sc[i0], xb = sc[i1];
    for (int l = 0; l < LC; ++l) {
        float xa_n = 0.f, xb_n = 0.f;
        if (l + 1 < LC) {                       // prefetch next step's x
            xa_n = sc[(l + 1) * SCP + i0];
            xb_n = sc[(l + 1) * SCP + i1];
        }
        float hm1  = dpp_shr1(h);               // h[m-1]
        float t    = is_m0 ? NEG : (hm1 + eps_r);
        float ae   = fmaxf(h, t);               // after_eps[m]
        float aem1 = dpp_shr1(ae);              // after_eps[m-1]
        float mn   = is_m0 ? 0.0f : (aem1 + xb);// main[m] (restart at m=0)
        h = fmaxf(mn, ae + xa);                 // max(main, self_loop)
        s = fmaxf(s, h);                        // only lane m==6 meaningful
        xa = xa_n; xb = xb_n;
    }
}

__global__ __launch_bounds__(512, 1)
void sopa_kernel(const uint16_t* __restrict__ A_ws,
                 const uint16_t* __restrict__ B_ws,
                 const float* __restrict__ epsilon,
                 float* __restrict__ scores_g)
{
    extern __shared__ char smem[];
    // LDS layout: [A buf0 | A buf1 | SC buf0 | SC buf1]

    const int blk = blockIdx.x;
    const int bb  = blk / NTILE;
    const int pt  = blk - bb * NTILE;
    const int d0  = pt * DT;
    const int p0  = pt * PT;

    const int tid  = threadIdx.x;
    const int wave = tid >> 6;
    const int lane = tid & 63;

    // MFMA-wave geometry (waves 0-3)
    const int rlo = lane & 15;
    const int kq  = lane >> 4;
    const int wr  = wave & 1;
    const int wc  = wave >> 1;
    const int cb  = wc * 4;                 // col-frag base: {0..3} or {4..6}
    const int nfr = (wc == 0) ? 4 : 3;
    const int arow  = wr * 16 + rlo;
    const int abase = arow * ROWB;
    const int aswz  = (arow & 7) << 4;

    // B fragments -> registers, once (prologue). Pre-swizzle undone via XOR
    // in the global address (B_ws holds unit j at j^(col&7)).
    bf16x8 breg[4][10];
    if (wave < 4) {
        const uint16_t* Bg = B_ws + (size_t)d0 * KP;
#pragma unroll
        for (int f = 0; f < 4; ++f) {
            if (f < nfr) {
                int col = (cb + f) * 16 + rlo;
#pragma unroll
                for (int kk = 0; kk < 10; ++kk) {
                    int jp = (kk * 4 + kq) ^ (col & 7);
                    breg[f][kk] = *reinterpret_cast<const bf16x8*>(
                        Bg + (size_t)col * KP + jp * 8);
                }
            }
        }
    }

    // prologue: stage A chunk 0
    {
        const uint4* a4 = (const uint4*)(A_ws + (size_t)(bb * NL) * KP);
        uint4* ad = (uint4*)smem;
        for (int u = tid; u < LDS_A / 16; u += 512) ad[u] = a4[u];
    }
    __syncthreads();

    // scan-wave state (wave 4): lane = p_local*8 + m  (m==7 lanes are dummies)
    const int  pp = lane >> 3;
    const int  mm = lane & 7;
    const bool is_m0 = (mm == 0);
    float eps_r = 0.0f;
    if (mm >= 1 && mm <= 6) eps_r = epsilon[(p0 + pp) * 6 + (mm - 1)];
    const int i0 = pp * 14 + mm;                       // x[p][0][m]
    const int i1 = pp * 14 + 7 + (mm ? mm - 1 : 0);    // x[p][1][m-1]
    float h = is_m0 ? 0.0f : NEG;
    float s = NEG;

    for (int c = 0; c < NCHUNK; ++c) {
        if (wave < 4) {
            const char* Ab  = smem + (c & 1) * LDS_A;
            float*      scw = (float*)(smem + 2 * LDS_A + (c & 1) * LDS_SC);
            if (wc == 0) mfma_body<4>(Ab, breg, scw, abase, aswz, cb, rlo, kq, wr);
            else         mfma_body<3>(Ab, breg, scw, abase, aswz, cb, rlo, kq, wr);
        } else if (wave == 4) {
            if (c > 0) {
                const float* scr = (const float*)(smem + 2 * LDS_A + ((c - 1) & 1) * LDS_SC);
                scan_chunk(scr, h, s, eps_r, is_m0, i0, i1);
            }
        } else {
            if (c + 1 < NCHUNK) {
                const uint4* s4 = (const uint4*)(A_ws + (size_t)(bb * NL + (c + 1) * LC) * KP);
                uint4* d4 = (uint4*)(smem + ((c + 1) & 1) * LDS_A);
                for (int u = tid - 320; u < LDS_A / 16; u += 192) d4[u] = s4[u];
            }
        }
        __syncthreads();
    }

    if (wave == 4) {
        const float* scr = (const float*)(smem + 2 * LDS_A + ((NCHUNK - 1) & 1) * LDS_SC);
        scan_chunk(scr, h, s, eps_r, is_m0, i0, i1);
        if (mm == 6) scores_g[bb * NP + p0 + pp] = s;
    }
}

// ---------------------------------------------------------------------------
// tiny MLP head: one block per batch row, fp32
// ---------------------------------------------------------------------------
__global__ void mlp_kernel(const float* __restrict__ scores_g,
                           const float* __restrict__ w1, const float* __restrict__ b1,
                           const float* __restrict__ w2, const float* __restrict__ b2,
                           const float* __restrict__ w3, const float* __restrict__ b3,
                           float* __restrict__ out)
{
    __shared__ float sc[NP];
    __shared__ float h1[NH];
    __shared__ float h2[NH];
    int b = blockIdx.x, t = threadIdx.x;
    for (int i = t; i < NP; i += blockDim.x) sc[i] = scores_g[b * NP + i];
    __syncthreads();
    if (t < NH) {
        float acc = b1[t];
        for (int k = 0; k < NP; ++k) acc += sc[k] * w1[k * NH + t];
        h1[t] = fmaxf(acc, 0.0f);
    }
    __syncthreads();
    if (t < NH) {
        float acc = b2[t];
        for (int k = 0; k < NH; ++k) acc += h1[k] * w2[k * NH + t];
        h2[t] = fmaxf(acc, 0.0f);
    }
    __syncthreads();
    if (t == 0) {
        float l0 = b3[0], l1 = b3[1];
        for (int k = 0; k < NH; ++k) { l0 += h2[k] * w3[k * 2]; l1 += h2[k] * w3[k * 2 + 1]; }
        float mx  = fmaxf(l0, l1);
        float lse = mx + logf(expf(l0 - mx) + expf(l1 - mx));
        out[b * 2 + 0] = l0 - lse;
        out[b * 2 + 1] = l1 - lse;
    }
}

extern "C" void kernel_launch(void* const* d_in, const int* in_sizes, int n_in,
                              void* d_out, int out_size, void* d_ws, size_t ws_size,
                              hipStream_t stream)
{
    const int*   docs  = (const int*)  d_in[0];
    const float* emb   = (const float*)d_in[1];
    const float* diags = (const float*)d_in[2];
    const float* bias  = (const float*)d_in[3];
    const float* eps   = (const float*)d_in[4];
    const float* w1 = (const float*)d_in[5];
    const float* b1 = (const float*)d_in[6];
    const float* w2 = (const float*)d_in[7];
    const float* b2 = (const float*)d_in[8];
    const float* w3 = (const float*)d_in[9];
    const float* b3 = (const float*)d_in[10];
    float* out = (float*)d_out;

    char* ws = (char*)d_ws;
    uint16_t* A_ws     = (uint16_t*)ws;                              // 20,971,520 B
    uint16_t* B_ws     = (uint16_t*)(ws + 20971520);                 //  1,792,000 B
    float*    scores_g = (float*)   (ws + 20971520 + 1792000);       //     51,200 B

    {
        int totalUnits = (NB * NL + ND) * UNITS;
        int blocks = (totalUnits + 255) / 256;
        prep_kernel<<<blocks, 256, 0, stream>>>(docs, emb, diags, bias, A_ws, B_ws);
    }

    (void)hipFuncSetAttribute(reinterpret_cast<const void*>(sopa_kernel),
                              hipFuncAttributeMaxDynamicSharedMemorySize, LDS_TOTAL);
    sopa_kernel<<<NB * NTILE, 512, LDS_TOTAL, stream>>>(A_ws, B_ws, eps, scores_g);

    mlp_kernel<<<NB, 128, 0, stream>>>(scores_g, w1, b1, w2, b2, w3, b3, out);
}

// Round 4
// 319.898 us; speedup vs baseline: 1.2004x; 1.1819x over previous
//
#include <hip/hip_runtime.h>
#include <stdint.h>

#define NEG (-100.0f)

#define NE 300      // embedding dim
#define NB 64       // batch
#define NL 512      // seq len
#define NP 200      // patterns
#define ND 2800     // diag rows = P*2*M
#define NH 100      // mlp hidden

#define KP 320      // padded K (300 emb + 1 bias-col + zeros)
#define UNITS 40    // 16B units per row (KP*2/16)
#define ROWB 640    // bytes per row

#define PT 8        // patterns per tile
#define DT 112      // diag rows per tile (PT*14)
#define NTILE 25    // pattern tiles (200/8)
#define LC 32       // l-chunk
#define NCHUNK 16   // 512/32
#define SCP 116     // score-tile stride in floats (4*SCP%128 == 64 -> 2-way only)

#define LDS_A   (LC*ROWB)          // 20480
#define LDS_SC  (LC*SCP*4)         // 14848
#define LDS_TOTAL (2*LDS_A + 2*LDS_SC)   // 70656

using f32x4  = __attribute__((ext_vector_type(4))) float;
using bf16x8 = __attribute__((ext_vector_type(8))) __bf16;

static __device__ __forceinline__ uint16_t f2bf(float f) {
    union { float f; uint32_t u; } v; v.f = f;
    return (uint16_t)((v.u + 0x7FFFu + ((v.u >> 16) & 1u)) >> 16);   // RNE
}

// keep-alive: forbids the compiler from rematerializing x from its source
static __device__ __forceinline__ void pin(bf16x8& x) {
    asm volatile("" : "+v"(x));
}

// lane i gets lane i-1's value (within rows of 16); row-lane 0 gets 0.
static __device__ __forceinline__ float dpp_shr1(float x) {
    int r = __builtin_amdgcn_update_dpp(0, __float_as_int(x), 0x111, 0xF, 0xF, true);
    return __int_as_float(r);
}

// ---------------------------------------------------------------------------
// prep: gather emb rows by docs, convert to bf16, pad K to 320 (col 300 = 1.0
// for A / bias[d] for B), store 16B units PRE-SWIZZLED (unit j at j^(row&7)).
// Fully vectorized: units 0..36 are two clean float4 loads; 37 is the
// boundary (4 floats + bias-col); 38/39 are zero fill.
// ---------------------------------------------------------------------------
__global__ void prep_kernel(const int* __restrict__ docs,
                            const float* __restrict__ emb,
                            const float* __restrict__ diags,
                            const float* __restrict__ bias,
                            uint16_t* __restrict__ A_ws,
                            uint16_t* __restrict__ B_ws)
{
    int tid = blockIdx.x * blockDim.x + threadIdx.x;
    const int totalA = NB * NL * UNITS;
    const int total  = totalA + ND * UNITS;
    if (tid >= total) return;
    const float* src; uint16_t* dst; float extra; int r, j;
    if (tid < totalA) {
        r = tid / UNITS; j = tid - r * UNITS;
        src = emb + (size_t)docs[r] * NE;
        dst = A_ws + (size_t)r * KP;
        extra = 1.0f;                       // bias column multiplier
    } else {
        int t2 = tid - totalA;
        r = t2 / UNITS; j = t2 - r * UNITS;
        src = diags + (size_t)r * NE;
        dst = B_ws + (size_t)r * KP;
        extra = bias[r];
    }
    int jp = j ^ (r & 7);                   // pre-swizzle 16B unit
    union { uint16_t h[8]; uint4 v; } u;
    if (j < 37) {                           // e0+7 = 36*8+7 = 295 < 300
        float4 f0 = *reinterpret_cast<const float4*>(src + j * 8);
        float4 f1 = *reinterpret_cast<const float4*>(src + j * 8 + 4);
        u.h[0] = f2bf(f0.x); u.h[1] = f2bf(f0.y);
        u.h[2] = f2bf(f0.z); u.h[3] = f2bf(f0.w);
        u.h[4] = f2bf(f1.x); u.h[5] = f2bf(f1.y);
        u.h[6] = f2bf(f1.z); u.h[7] = f2bf(f1.w);
    } else if (j == 37) {                   // elems 296..299 real, 300 = extra
        float4 f0 = *reinterpret_cast<const float4*>(src + 296);
        u.h[0] = f2bf(f0.x); u.h[1] = f2bf(f0.y);
        u.h[2] = f2bf(f0.z); u.h[3] = f2bf(f0.w);
        u.h[4] = f2bf(extra); u.h[5] = 0; u.h[6] = 0; u.h[7] = 0;
    } else {                                // zero pad
        u.v = uint4{0, 0, 0, 0};
    }
    *reinterpret_cast<uint4*>(dst + (size_t)jp * 8) = u.v;
}

// ---------------------------------------------------------------------------
// fused GEMM (bf16 MFMA 16x16x32, B pinned in registers) + max-plus scan.
// 8 waves: 0-3 MFMA (2x2 wave grid over 32 rows x 112 cols), 4 scan,
// 5-7 A staging (double-buffered, issue-all-then-write).
// ---------------------------------------------------------------------------
template<int NFR>
static __device__ __forceinline__ void mfma_body(const char* __restrict__ Ab,
    const bf16x8 (&breg)[4][10], float* __restrict__ scw,
    int abase, int aswz, int cb, int rlo, int kq, int wr)
{
    f32x4 acc[NFR];
#pragma unroll
    for (int f = 0; f < NFR; ++f) acc[f] = f32x4{0.f, 0.f, 0.f, 0.f};
#pragma unroll
    for (int kk = 0; kk < KP / 32; ++kk) {
        int ab = abase + kk * 64 + kq * 16;
        bf16x8 av = *reinterpret_cast<const bf16x8*>(Ab + (ab ^ aswz));
#pragma unroll
        for (int f = 0; f < NFR; ++f)
            acc[f] = __builtin_amdgcn_mfma_f32_16x16x32_bf16(av, breg[f][kk], acc[f], 0, 0, 0);
    }
    const int crow = wr * 16 + kq * 4;      // C/D: col=lane&15, row=(lane>>4)*4+reg
#pragma unroll
    for (int f = 0; f < NFR; ++f) {
        int col = (cb + f) * 16 + rlo;
#pragma unroll
        for (int rr = 0; rr < 4; ++rr)
            scw[(crow + rr) * SCP + col] = acc[f][rr];
    }
}

static __device__ __forceinline__ void scan_chunk(const float* __restrict__ sc,
        float& h, float& s, float eps_r, bool is_m0, int i0, int i1)
{
    float xa = sc[i0], xb = sc[i1];
    for (int l = 0; l < LC; ++l) {
        float xa_n = 0.f, xb_n = 0.f;
        if (l + 1 < LC) {                       // prefetch next step's x
            xa_n = sc[(l + 1) * SCP + i0];
            xb_n = sc[(l + 1) * SCP + i1];
        }
        float hm1  = dpp_shr1(h);               // h[m-1]
        float t    = is_m0 ? NEG : (hm1 + eps_r);
        float ae   = fmaxf(h, t);               // after_eps[m]
        float aem1 = dpp_shr1(ae);              // after_eps[m-1]
        float mn   = is_m0 ? 0.0f : (aem1 + xb);// main[m] (restart at m=0)
        h = fmaxf(mn, ae + xa);                 // max(main, self_loop)
        s = fmaxf(s, h);                        // only lane m==6 meaningful
        xa = xa_n; xb = xb_n;
    }
}

__global__ __launch_bounds__(512, 2)
void sopa_kernel(const uint16_t* __restrict__ A_ws,
                 const uint16_t* __restrict__ B_ws,
                 const float* __restrict__ epsilon,
                 float* __restrict__ scores_g)
{
    extern __shared__ char smem[];
    // LDS layout: [A buf0 | A buf1 | SC buf0 | SC buf1]

    const int blk = blockIdx.x;
    const int bb  = blk / NTILE;
    const int pt  = blk - bb * NTILE;
    const int d0  = pt * DT;
    const int p0  = pt * PT;

    const int tid  = threadIdx.x;
    const int wave = tid >> 6;
    const int lane = tid & 63;

    // MFMA-wave geometry (waves 0-3)
    const int rlo = lane & 15;
    const int kq  = lane >> 4;
    const int wr  = wave & 1;
    const int wc  = wave >> 1;
    const int cb  = wc * 4;                 // col-frag base: {0..3} or {4..6}
    const int nfr = (wc == 0) ? 4 : 3;
    const int arow  = wr * 16 + rlo;
    const int abase = arow * ROWB;
    const int aswz  = (arow & 7) << 4;

    // B fragments -> registers, once. Pre-swizzle undone via XOR in the
    // global address (B_ws holds unit j at j^(col&7)). asm pin forbids remat.
    bf16x8 breg[4][10];
    if (wave < 4) {
        const uint16_t* Bg = B_ws + (size_t)d0 * KP;
#pragma unroll
        for (int f = 0; f < 4; ++f) {
#pragma unroll
            for (int kk = 0; kk < 10; ++kk) {
                if (f < nfr) {
                    int col = (cb + f) * 16 + rlo;
                    int jp  = (kk * 4 + kq) ^ (col & 7);
                    breg[f][kk] = *reinterpret_cast<const bf16x8*>(
                        Bg + (size_t)col * KP + jp * 8);
                } else {
                    breg[f][kk] = bf16x8{0,0,0,0,0,0,0,0};
                }
                pin(breg[f][kk]);
            }
        }
    }

    // prologue: stage A chunk 0
    {
        const uint4* a4 = (const uint4*)(A_ws + (size_t)(bb * NL) * KP);
        uint4* ad = (uint4*)smem;
        for (int u = tid; u < LDS_A / 16; u += 512) ad[u] = a4[u];
    }
    __syncthreads();

    // scan-wave state (wave 4): lane = p_local*8 + m  (m==7 lanes are dummies)
    const int  pp = lane >> 3;
    const int  mm = lane & 7;
    const bool is_m0 = (mm == 0);
    float eps_r = 0.0f;
    if (mm >= 1 && mm <= 6) eps_r = epsilon[(p0 + pp) * 6 + (mm - 1)];
    const int i0 = pp * 14 + mm;                       // x[p][0][m]
    const int i1 = pp * 14 + 7 + (mm ? mm - 1 : 0);    // x[p][1][m-1]
    float h = is_m0 ? 0.0f : NEG;
    float s = NEG;

    for (int c = 0; c < NCHUNK; ++c) {
        if (wave < 4) {
            const char* Ab  = smem + (c & 1) * LDS_A;
            float*      scw = (float*)(smem + 2 * LDS_A + (c & 1) * LDS_SC);
            if (wc == 0) mfma_body<4>(Ab, breg, scw, abase, aswz, cb, rlo, kq, wr);
            else         mfma_body<3>(Ab, breg, scw, abase, aswz, cb, rlo, kq, wr);
        } else if (wave == 4) {
            if (c > 0) {
                const float* scr = (const float*)(smem + 2 * LDS_A + ((c - 1) & 1) * LDS_SC);
                scan_chunk(scr, h, s, eps_r, is_m0, i0, i1);
            }
        } else {
            // waves 5-7: stage next A chunk. Issue ALL loads, then all writes
            // (one latency round trip instead of 7 dependent ones).
            if (c + 1 < NCHUNK) {
                const uint4* s4 = (const uint4*)(A_ws + (size_t)(bb * NL + (c + 1) * LC) * KP);
                uint4* d4 = (uint4*)(smem + ((c + 1) & 1) * LDS_A);
                const int sl = tid - 320;                    // 0..191
                uint4 r0 = s4[sl];
                uint4 r1 = s4[sl + 192];
                uint4 r2 = s4[sl + 384];
                uint4 r3 = s4[sl + 576];
                uint4 r4 = s4[sl + 768];
                uint4 r5 = s4[sl + 960];
                uint4 r6 = uint4{0, 0, 0, 0};
                const bool t6 = sl < (LDS_A / 16 - 1152);    // 128 tail units
                if (t6) r6 = s4[sl + 1152];
                d4[sl]       = r0;
                d4[sl + 192] = r1;
                d4[sl + 384] = r2;
                d4[sl + 576] = r3;
                d4[sl + 768] = r4;
                d4[sl + 960] = r5;
                if (t6) d4[sl + 1152] = r6;
            }
        }
        __syncthreads();
    }

    if (wave == 4) {
        const float* scr = (const float*)(smem + 2 * LDS_A + ((NCHUNK - 1) & 1) * LDS_SC);
        scan_chunk(scr, h, s, eps_r, is_m0, i0, i1);
        if (mm == 6) scores_g[bb * NP + p0 + pp] = s;
    }
}

// ---------------------------------------------------------------------------
// tiny MLP head: one block per batch row, fp32
// ---------------------------------------------------------------------------
__global__ void mlp_kernel(const float* __restrict__ scores_g,
                           const float* __restrict__ w1, const float* __restrict__ b1,
                           const float* __restrict__ w2, const float* __restrict__ b2,
                           const float* __restrict__ w3, const float* __restrict__ b3,
                           float* __restrict__ out)
{
    __shared__ float sc[NP];
    __shared__ float h1[NH];
    __shared__ float h2[NH];
    int b = blockIdx.x, t = threadIdx.x;
    for (int i = t; i < NP; i += blockDim.x) sc[i] = scores_g[b * NP + i];
    __syncthreads();
    if (t < NH) {
        float acc = b1[t];
#pragma unroll 8
        for (int k = 0; k < NP; ++k) acc += sc[k] * w1[k * NH + t];
        h1[t] = fmaxf(acc, 0.0f);
    }
    __syncthreads();
    if (t < NH) {
        float acc = b2[t];
#pragma unroll 8
        for (int k = 0; k < NH; ++k) acc += h1[k] * w2[k * NH + t];
        h2[t] = fmaxf(acc, 0.0f);
    }
    __syncthreads();
    if (t < 64) {
        float l0 = 0.0f, l1 = 0.0f;
        for (int k = t; k < NH; k += 64) {
            float hv = h2[k];
            l0 += hv * w3[k * 2];
            l1 += hv * w3[k * 2 + 1];
        }
#pragma unroll
        for (int off = 32; off > 0; off >>= 1) {
            l0 += __shfl_down(l0, off);
            l1 += __shfl_down(l1, off);
        }
        if (t == 0) {
            l0 += b3[0]; l1 += b3[1];
            float mx  = fmaxf(l0, l1);
            float lse = mx + logf(expf(l0 - mx) + expf(l1 - mx));
            out[b * 2 + 0] = l0 - lse;
            out[b * 2 + 1] = l1 - lse;
        }
    }
}

extern "C" void kernel_launch(void* const* d_in, const int* in_sizes, int n_in,
                              void* d_out, int out_size, void* d_ws, size_t ws_size,
                              hipStream_t stream)
{
    const int*   docs  = (const int*)  d_in[0];
    const float* emb   = (const float*)d_in[1];
    const float* diags = (const float*)d_in[2];
    const float* bias  = (const float*)d_in[3];
    const float* eps   = (const float*)d_in[4];
    const float* w1 = (const float*)d_in[5];
    const float* b1 = (const float*)d_in[6];
    const float* w2 = (const float*)d_in[7];
    const float* b2 = (const float*)d_in[8];
    const float* w3 = (const float*)d_in[9];
    const float* b3 = (const float*)d_in[10];
    float* out = (float*)d_out;

    char* ws = (char*)d_ws;
    uint16_t* A_ws     = (uint16_t*)ws;                              // 20,971,520 B
    uint16_t* B_ws     = (uint16_t*)(ws + 20971520);                 //  1,792,000 B
    float*    scores_g = (float*)   (ws + 20971520 + 1792000);       //     51,200 B

    {
        int totalUnits = (NB * NL + ND) * UNITS;
        int blocks = (totalUnits + 255) / 256;
        prep_kernel<<<blocks, 256, 0, stream>>>(docs, emb, diags, bias, A_ws, B_ws);
    }

    (void)hipFuncSetAttribute(reinterpret_cast<const void*>(sopa_kernel),
                              hipFuncAttributeMaxDynamicSharedMemorySize, LDS_TOTAL);
    sopa_kernel<<<NB * NTILE, 512, LDS_TOTAL, stream>>>(A_ws, B_ws, eps, scores_g);

    mlp_kernel<<<NB, 128, 0, stream>>>(scores_g, w1, b1, w2, b2, w3, b3, out);
}

// Round 5
// 308.752 us; speedup vs baseline: 1.2438x; 1.0361x over previous
//
#include <hip/hip_runtime.h>
#include <stdint.h>

#define NEG (-100.0f)

#define NE 300      // embedding dim
#define NB 64       // batch
#define NL 512      // seq len
#define NP 200      // patterns
#define ND 2800     // diag rows = P*2*M
#define NH 100      // mlp hidden

#define KP 320      // padded K (300 emb + 1 bias-col + zeros)
#define UNITS 40    // 16B units per row (KP*2/16)
#define ROWB 640    // bytes per row

#define PT 8        // patterns per tile
#define DT 112      // diag rows per tile (PT*14)
#define NTILE 25    // pattern tiles (200/8)
#define LC 32       // l-chunk
#define NCHUNK 16   // 512/32
#define SCW 36      // transposed score tile: sc[col][l], stride 36 floats (16B-aligned)

#define LDS_A   (LC*ROWB)          // 20480
#define LDS_SC  (DT*SCW*4)         // 16128
#define LDS_TOTAL (2*LDS_A + 2*LDS_SC)   // 73216

using f32x4  = __attribute__((ext_vector_type(4))) float;
using bf16x8 = __attribute__((ext_vector_type(8))) __bf16;

static __device__ __forceinline__ uint16_t f2bf(float f) {
    union { float f; uint32_t u; } v; v.f = f;
    return (uint16_t)((v.u + 0x7FFFu + ((v.u >> 16) & 1u)) >> 16);   // RNE
}

// keep-alive: forbids the compiler from rematerializing x from its source
static __device__ __forceinline__ void pin(bf16x8& x) {
    asm volatile("" : "+v"(x));
}

// lane i gets lane i-1's value (within rows of 16); row-lane 0 gets 0.
static __device__ __forceinline__ float dpp_shr1(float x) {
    int r = __builtin_amdgcn_update_dpp(0, __float_as_int(x), 0x111, 0xF, 0xF, true);
    return __int_as_float(r);
}

// ---------------------------------------------------------------------------
// prep: gather emb rows by docs, convert to bf16, pad K to 320 (col 300 = 1.0
// for A / bias[d] for B), store 16B units PRE-SWIZZLED (unit j at j^(row&7)).
// ---------------------------------------------------------------------------
__global__ void prep_kernel(const int* __restrict__ docs,
                            const float* __restrict__ emb,
                            const float* __restrict__ diags,
                            const float* __restrict__ bias,
                            uint16_t* __restrict__ A_ws,
                            uint16_t* __restrict__ B_ws)
{
    int tid = blockIdx.x * blockDim.x + threadIdx.x;
    const int totalA = NB * NL * UNITS;
    const int total  = totalA + ND * UNITS;
    if (tid >= total) return;
    const float* src; uint16_t* dst; float extra; int r, j;
    if (tid < totalA) {
        r = tid / UNITS; j = tid - r * UNITS;
        src = emb + (size_t)docs[r] * NE;
        dst = A_ws + (size_t)r * KP;
        extra = 1.0f;                       // bias column multiplier
    } else {
        int t2 = tid - totalA;
        r = t2 / UNITS; j = t2 - r * UNITS;
        src = diags + (size_t)r * NE;
        dst = B_ws + (size_t)r * KP;
        extra = bias[r];
    }
    int jp = j ^ (r & 7);                   // pre-swizzle 16B unit
    union { uint16_t h[8]; uint4 v; } u;
    if (j < 37) {                           // e0+7 = 36*8+7 = 295 < 300
        float4 f0 = *reinterpret_cast<const float4*>(src + j * 8);
        float4 f1 = *reinterpret_cast<const float4*>(src + j * 8 + 4);
        u.h[0] = f2bf(f0.x); u.h[1] = f2bf(f0.y);
        u.h[2] = f2bf(f0.z); u.h[3] = f2bf(f0.w);
        u.h[4] = f2bf(f1.x); u.h[5] = f2bf(f1.y);
        u.h[6] = f2bf(f1.z); u.h[7] = f2bf(f1.w);
    } else if (j == 37) {                   // elems 296..299 real, 300 = extra
        float4 f0 = *reinterpret_cast<const float4*>(src + 296);
        u.h[0] = f2bf(f0.x); u.h[1] = f2bf(f0.y);
        u.h[2] = f2bf(f0.z); u.h[3] = f2bf(f0.w);
        u.h[4] = f2bf(extra); u.h[5] = 0; u.h[6] = 0; u.h[7] = 0;
    } else {                                // zero pad
        u.v = uint4{0, 0, 0, 0};
    }
    *reinterpret_cast<uint4*>(dst + (size_t)jp * 8) = u.v;
}

// ---------------------------------------------------------------------------
// fused GEMM (bf16 MFMA 16x16x32, B pinned in registers) + max-plus scan.
// 8 waves: 0-3 MFMA, 4 scan, 5-7 A staging (double-buffered).
// Score tile is TRANSPOSED in LDS: sc[col*SCW + l]  (col = diag row, l = step)
//  - MFMA epilogue: acc[f] (4 row-consecutive values) = one ds_write_b128
//  - scan wave: preloads all 32 steps via 16 ds_read_b128, then pure VALU
// ---------------------------------------------------------------------------
template<int NFR>
static __device__ __forceinline__ void mfma_body(const char* __restrict__ Ab,
    const bf16x8 (&breg)[4][10], float* __restrict__ scw,
    int abase, int aswz, int cb, int rlo, int kq, int wr)
{
    f32x4 acc[NFR];
#pragma unroll
    for (int f = 0; f < NFR; ++f) acc[f] = f32x4{0.f, 0.f, 0.f, 0.f};
#pragma unroll
    for (int kk = 0; kk < KP / 32; ++kk) {
        int ab = abase + kk * 64 + kq * 16;
        bf16x8 av = *reinterpret_cast<const bf16x8*>(Ab + (ab ^ aswz));
#pragma unroll
        for (int f = 0; f < NFR; ++f)
            acc[f] = __builtin_amdgcn_mfma_f32_16x16x32_bf16(av, breg[f][kk], acc[f], 0, 0, 0);
    }
    const int crow = wr * 16 + kq * 4;      // C/D: col=lane&15, row=(lane>>4)*4+reg
#pragma unroll
    for (int f = 0; f < NFR; ++f) {
        int col = (cb + f) * 16 + rlo;
        *reinterpret_cast<f32x4*>(scw + col * SCW + crow) = acc[f];
    }
}

static __device__ __forceinline__ void scan_chunk(const float* __restrict__ sc,
        float& h, float& s, float eps_r, bool is_m0, int i0, int i1)
{
    // preload the whole chunk: xa[l] = sc[i0*SCW + l], xb[l] = sc[i1*SCW + l]
    f32x4 xav[8], xbv[8];
#pragma unroll
    for (int i = 0; i < 8; ++i)
        xav[i] = *reinterpret_cast<const f32x4*>(sc + i0 * SCW + i * 4);
#pragma unroll
    for (int i = 0; i < 8; ++i)
        xbv[i] = *reinterpret_cast<const f32x4*>(sc + i1 * SCW + i * 4);
#pragma unroll
    for (int l = 0; l < LC; ++l) {
        float xa = xav[l >> 2][l & 3];
        float xb = xbv[l >> 2][l & 3];
        float hm1  = dpp_shr1(h);               // h[m-1]
        float t    = is_m0 ? NEG : (hm1 + eps_r);
        float ae   = fmaxf(h, t);               // after_eps[m]
        float aem1 = dpp_shr1(ae);              // after_eps[m-1]
        float mn   = is_m0 ? 0.0f : (aem1 + xb);// main[m] (restart at m=0)
        h = fmaxf(mn, ae + xa);                 // max(main, self_loop)
        s = fmaxf(s, h);                        // only lane m==6 meaningful
    }
}

__global__ __launch_bounds__(512, 2)
void sopa_kernel(const uint16_t* __restrict__ A_ws,
                 const uint16_t* __restrict__ B_ws,
                 const float* __restrict__ epsilon,
                 float* __restrict__ scores_g)
{
    extern __shared__ char smem[];
    // LDS layout: [A buf0 | A buf1 | SC buf0 | SC buf1]

    const int blk = blockIdx.x;
    const int bb  = blk / NTILE;
    const int pt  = blk - bb * NTILE;
    const int d0  = pt * DT;
    const int p0  = pt * PT;

    const int tid  = threadIdx.x;
    const int wave = tid >> 6;
    const int lane = tid & 63;

    // MFMA-wave geometry (waves 0-3)
    const int rlo = lane & 15;
    const int kq  = lane >> 4;
    const int wr  = wave & 1;
    const int wc  = wave >> 1;
    const int cb  = wc * 4;                 // col-frag base: {0..3} or {4..6}
    const int nfr = (wc == 0) ? 4 : 3;
    const int arow  = wr * 16 + rlo;
    const int abase = arow * ROWB;
    const int aswz  = (arow & 7) << 4;

    // B fragments -> registers, once. Pre-swizzle undone via XOR in the
    // global address (B_ws holds unit j at j^(col&7)). asm pin forbids remat.
    bf16x8 breg[4][10];
    if (wave < 4) {
        const uint16_t* Bg = B_ws + (size_t)d0 * KP;
#pragma unroll
        for (int f = 0; f < 4; ++f) {
#pragma unroll
            for (int kk = 0; kk < 10; ++kk) {
                if (f < nfr) {
                    int col = (cb + f) * 16 + rlo;
                    int jp  = (kk * 4 + kq) ^ (col & 7);
                    breg[f][kk] = *reinterpret_cast<const bf16x8*>(
                        Bg + (size_t)col * KP + jp * 8);
                } else {
                    breg[f][kk] = bf16x8{0,0,0,0,0,0,0,0};
                }
                pin(breg[f][kk]);
            }
        }
    }

    // prologue: stage A chunk 0
    {
        const uint4* a4 = (const uint4*)(A_ws + (size_t)(bb * NL) * KP);
        uint4* ad = (uint4*)smem;
        for (int u = tid; u < LDS_A / 16; u += 512) ad[u] = a4[u];
    }
    __syncthreads();

    // scan-wave state (wave 4): lane = p_local*8 + m  (m==7 lanes are dummies)
    const int  pp = lane >> 3;
    const int  mm = lane & 7;
    const bool is_m0 = (mm == 0);
    float eps_r = 0.0f;
    if (mm >= 1 && mm <= 6) eps_r = epsilon[(p0 + pp) * 6 + (mm - 1)];
    const int i0 = pp * 14 + mm;                       // x[p][0][m]
    const int i1 = pp * 14 + 7 + (mm ? mm - 1 : 0);    // x[p][1][m-1]
    float h = is_m0 ? 0.0f : NEG;
    float s = NEG;

    for (int c = 0; c < NCHUNK; ++c) {
        if (wave < 4) {
            const char* Ab  = smem + (c & 1) * LDS_A;
            float*      scw = (float*)(smem + 2 * LDS_A + (c & 1) * LDS_SC);
            if (wc == 0) mfma_body<4>(Ab, breg, scw, abase, aswz, cb, rlo, kq, wr);
            else         mfma_body<3>(Ab, breg, scw, abase, aswz, cb, rlo, kq, wr);
        } else if (wave == 4) {
            if (c > 0) {
                const float* scr = (const float*)(smem + 2 * LDS_A + ((c - 1) & 1) * LDS_SC);
                scan_chunk(scr, h, s, eps_r, is_m0, i0, i1);
            }
        } else {
            // waves 5-7: stage next A chunk. Issue ALL loads, then all writes
            // (one latency round trip instead of 7 dependent ones).
            if (c + 1 < NCHUNK) {
                const uint4* s4 = (const uint4*)(A_ws + (size_t)(bb * NL + (c + 1) * LC) * KP);
                uint4* d4 = (uint4*)(smem + ((c + 1) & 1) * LDS_A);
                const int sl = tid - 320;                    // 0..191
                uint4 r0 = s4[sl];
                uint4 r1 = s4[sl + 192];
                uint4 r2 = s4[sl + 384];
                uint4 r3 = s4[sl + 576];
                uint4 r4 = s4[sl + 768];
                uint4 r5 = s4[sl + 960];
                uint4 r6 = uint4{0, 0, 0, 0};
                const bool t6 = sl < (LDS_A / 16 - 1152);    // 128 tail units
                if (t6) r6 = s4[sl + 1152];
                d4[sl]       = r0;
                d4[sl + 192] = r1;
                d4[sl + 384] = r2;
                d4[sl + 576] = r3;
                d4[sl + 768] = r4;
                d4[sl + 960] = r5;
                if (t6) d4[sl + 1152] = r6;
            }
        }
        __syncthreads();
    }

    if (wave == 4) {
        const float* scr = (const float*)(smem + 2 * LDS_A + ((NCHUNK - 1) & 1) * LDS_SC);
        scan_chunk(scr, h, s, eps_r, is_m0, i0, i1);
        if (mm == 6) scores_g[bb * NP + p0 + pp] = s;
    }
}

// ---------------------------------------------------------------------------
// tiny MLP head: one block per batch row, fp32
// ---------------------------------------------------------------------------
__global__ void mlp_kernel(const float* __restrict__ scores_g,
                           const float* __restrict__ w1, const float* __restrict__ b1,
                           const float* __restrict__ w2, const float* __restrict__ b2,
                           const float* __restrict__ w3, const float* __restrict__ b3,
                           float* __restrict__ out)
{
    __shared__ float sc[NP];
    __shared__ float h1[NH];
    __shared__ float h2[NH];
    int b = blockIdx.x, t = threadIdx.x;
    for (int i = t; i < NP; i += blockDim.x) sc[i] = scores_g[b * NP + i];
    __syncthreads();
    if (t < NH) {
        float acc = b1[t];
#pragma unroll 8
        for (int k = 0; k < NP; ++k) acc += sc[k] * w1[k * NH + t];
        h1[t] = fmaxf(acc, 0.0f);
    }
    __syncthreads();
    if (t < NH) {
        float acc = b2[t];
#pragma unroll 8
        for (int k = 0; k < NH; ++k) acc += h1[k] * w2[k * NH + t];
        h2[t] = fmaxf(acc, 0.0f);
    }
    __syncthreads();
    if (t < 64) {
        float l0 = 0.0f, l1 = 0.0f;
        for (int k = t; k < NH; k += 64) {
            float hv = h2[k];
            l0 += hv * w3[k * 2];
            l1 += hv * w3[k * 2 + 1];
        }
#pragma unroll
        for (int off = 32; off > 0; off >>= 1) {
            l0 += __shfl_down(l0, off);
            l1 += __shfl_down(l1, off);
        }
        if (t == 0) {
            l0 += b3[0]; l1 += b3[1];
            float mx  = fmaxf(l0, l1);
            float lse = mx + logf(expf(l0 - mx) + expf(l1 - mx));
            out[b * 2 + 0] = l0 - lse;
            out[b * 2 + 1] = l1 - lse;
        }
    }
}

extern "C" void kernel_launch(void* const* d_in, const int* in_sizes, int n_in,
                              void* d_out, int out_size, void* d_ws, size_t ws_size,
                              hipStream_t stream)
{
    const int*   docs  = (const int*)  d_in[0];
    const float* emb   = (const float*)d_in[1];
    const float* diags = (const float*)d_in[2];
    const float* bias  = (const float*)d_in[3];
    const float* eps   = (const float*)d_in[4];
    const float* w1 = (const float*)d_in[5];
    const float* b1 = (const float*)d_in[6];
    const float* w2 = (const float*)d_in[7];
    const float* b2 = (const float*)d_in[8];
    const float* w3 = (const float*)d_in[9];
    const float* b3 = (const float*)d_in[10];
    float* out = (float*)d_out;

    char* ws = (char*)d_ws;
    uint16_t* A_ws     = (uint16_t*)ws;                              // 20,971,520 B
    uint16_t* B_ws     = (uint16_t*)(ws + 20971520);                 //  1,792,000 B
    float*    scores_g = (float*)   (ws + 20971520 + 1792000);       //     51,200 B

    {
        int totalUnits = (NB * NL + ND) * UNITS;
        int blocks = (totalUnits + 255) / 256;
        prep_kernel<<<blocks, 256, 0, stream>>>(docs, emb, diags, bias, A_ws, B_ws);
    }

    (void)hipFuncSetAttribute(reinterpret_cast<const void*>(sopa_kernel),
                              hipFuncAttributeMaxDynamicSharedMemorySize, LDS_TOTAL);
    sopa_kernel<<<NB * NTILE, 512, LDS_TOTAL, stream>>>(A_ws, B_ws, eps, scores_g);

    mlp_kernel<<<NB, 128, 0, stream>>>(scores_g, w1, b1, w2, b2, w3, b3, out);
}

// Round 6
// 303.669 us; speedup vs baseline: 1.2646x; 1.0167x over previous
//
#include <hip/hip_runtime.h>
#include <stdint.h>

#define NEG (-100.0f)

#define NE 300      // embedding dim
#define NB 64       // batch
#define NL 512      // seq len
#define NP 200      // patterns
#define ND 2800     // diag rows = P*2*M
#define NDP 2816    // padded B rows (16 junk rows read by unconditional breg loads)
#define NH 100      // mlp hidden

#define KP 320      // padded K (300 emb + 1 bias-col + zeros)
#define UNITS 40    // 16B units per row (KP*2/16)
#define ROWB 640    // bytes per row

#define PT 8        // patterns per tile
#define DT 112      // diag rows per tile (PT*14)
#define NTILE 25    // pattern tiles (200/8)
#define LC 32       // l-chunk
#define NCHUNK 16   // 512/32
#define SCW 36      // transposed score tile: sc[col][l], stride 36 floats

#define LDS_A   (LC*ROWB)          // 20480
#define LDS_SC  (DT*SCW*4)         // 16128
#define LDS_TOTAL (3*LDS_A + 2*LDS_SC)   // 93696

using f32x4  = __attribute__((ext_vector_type(4))) float;
using bf16x8 = __attribute__((ext_vector_type(8))) __bf16;

// raw barrier (no compiler vmcnt/lgkmcnt drain) + counted waits (T3/T4)
#define SBAR()       asm volatile("s_barrier" ::: "memory")
#define WAIT_LGKM0() do { asm volatile("s_waitcnt lgkmcnt(0)" ::: "memory"); \
                          __builtin_amdgcn_sched_barrier(0); } while (0)
#define WAIT_VM(N)   do { asm volatile("s_waitcnt vmcnt(" #N ")" ::: "memory"); \
                          __builtin_amdgcn_sched_barrier(0); } while (0)

static __device__ __forceinline__ void gload16(const void* g, void* l) {
    __builtin_amdgcn_global_load_lds(
        (const __attribute__((address_space(1))) void*)g,
        (__attribute__((address_space(3))) void*)l, 16, 0, 0);
}

static __device__ __forceinline__ uint16_t f2bf(float f) {
    union { float f; uint32_t u; } v; v.f = f;
    return (uint16_t)((v.u + 0x7FFFu + ((v.u >> 16) & 1u)) >> 16);   // RNE
}

// keep-alive: forbids rematerialization/demotion of x
static __device__ __forceinline__ void pin(bf16x8& x) {
    asm volatile("" : "+v"(x));
}

// lane i gets lane i-1's value (within rows of 16); row-lane 0 gets 0.
static __device__ __forceinline__ float dpp_shr1(float x) {
    int r = __builtin_amdgcn_update_dpp(0, __float_as_int(x), 0x111, 0xF, 0xF, true);
    return __int_as_float(r);
}

// ---------------------------------------------------------------------------
// prep: gather emb rows by docs, convert to bf16, pad K to 320 (col 300 = 1.0
// for A / bias[d] for B), store 16B units PRE-SWIZZLED (unit j at j^(row&7)).
// ---------------------------------------------------------------------------
__global__ void prep_kernel(const int* __restrict__ docs,
                            const float* __restrict__ emb,
                            const float* __restrict__ diags,
                            const float* __restrict__ bias,
                            uint16_t* __restrict__ A_ws,
                            uint16_t* __restrict__ B_ws)
{
    int tid = blockIdx.x * blockDim.x + threadIdx.x;
    const int totalA = NB * NL * UNITS;
    const int total  = totalA + ND * UNITS;
    if (tid >= total) return;
    const float* src; uint16_t* dst; float extra; int r, j;
    if (tid < totalA) {
        r = tid / UNITS; j = tid - r * UNITS;
        src = emb + (size_t)docs[r] * NE;
        dst = A_ws + (size_t)r * KP;
        extra = 1.0f;                       // bias column multiplier
    } else {
        int t2 = tid - totalA;
        r = t2 / UNITS; j = t2 - r * UNITS;
        src = diags + (size_t)r * NE;
        dst = B_ws + (size_t)r * KP;
        extra = bias[r];
    }
    int jp = j ^ (r & 7);                   // pre-swizzle 16B unit
    union { uint16_t h[8]; uint4 v; } u;
    if (j < 37) {                           // e0+7 = 36*8+7 = 295 < 300
        float4 f0 = *reinterpret_cast<const float4*>(src + j * 8);
        float4 f1 = *reinterpret_cast<const float4*>(src + j * 8 + 4);
        u.h[0] = f2bf(f0.x); u.h[1] = f2bf(f0.y);
        u.h[2] = f2bf(f0.z); u.h[3] = f2bf(f0.w);
        u.h[4] = f2bf(f1.x); u.h[5] = f2bf(f1.y);
        u.h[6] = f2bf(f1.z); u.h[7] = f2bf(f1.w);
    } else if (j == 37) {                   // elems 296..299 real, 300 = extra
        float4 f0 = *reinterpret_cast<const float4*>(src + 296);
        u.h[0] = f2bf(f0.x); u.h[1] = f2bf(f0.y);
        u.h[2] = f2bf(f0.z); u.h[3] = f2bf(f0.w);
        u.h[4] = f2bf(extra); u.h[5] = 0; u.h[6] = 0; u.h[7] = 0;
    } else {                                // zero pad
        u.v = uint4{0, 0, 0, 0};
    }
    *reinterpret_cast<uint4*>(dst + (size_t)jp * 8) = u.v;
}

// ---------------------------------------------------------------------------
// fused GEMM (bf16 MFMA 16x16x32, B pinned in registers) + max-plus scan.
// 8 waves: 0-3 MFMA (2x2 wave grid), 4-5 scan (4 patterns each),
// 6-7 stagers (global_load_lds, 2 chunks ahead, A triple-buffered,
// counted vmcnt across raw s_barrier -- loads stay in flight).
// ---------------------------------------------------------------------------
template<int NFR>
static __device__ __forceinline__ void mfma_body(const char* __restrict__ Ab,
    const bf16x8 (&breg)[40], float* __restrict__ scw,
    int abase, int aswz, int cb, int rlo, int kq, int wr)
{
    f32x4 acc[NFR];
#pragma unroll
    for (int f = 0; f < NFR; ++f) acc[f] = f32x4{0.f, 0.f, 0.f, 0.f};
#pragma unroll
    for (int kk = 0; kk < KP / 32; ++kk) {
        int ab = abase + kk * 64 + kq * 16;
        bf16x8 av = *reinterpret_cast<const bf16x8*>(Ab + (ab ^ aswz));
#pragma unroll
        for (int f = 0; f < NFR; ++f)
            acc[f] = __builtin_amdgcn_mfma_f32_16x16x32_bf16(av, breg[f * 10 + kk], acc[f], 0, 0, 0);
    }
    const int crow = wr * 16 + kq * 4;      // C/D: col=lane&15, row=(lane>>4)*4+reg
#pragma unroll
    for (int f = 0; f < NFR; ++f) {
        int col = (cb + f) * 16 + rlo;
        *reinterpret_cast<f32x4*>(scw + col * SCW + crow) = acc[f];
    }
}

static __device__ __forceinline__ void scan_chunk(const float* __restrict__ sc,
        float& h, float& s, float eps_r, bool is_m0, int i0, int i1)
{
    // preload the whole chunk: xa[l] = sc[i0*SCW + l], xb[l] = sc[i1*SCW + l]
    f32x4 xav[8], xbv[8];
#pragma unroll
    for (int i = 0; i < 8; ++i)
        xav[i] = *reinterpret_cast<const f32x4*>(sc + i0 * SCW + i * 4);
#pragma unroll
    for (int i = 0; i < 8; ++i)
        xbv[i] = *reinterpret_cast<const f32x4*>(sc + i1 * SCW + i * 4);
#pragma unroll
    for (int l = 0; l < LC; ++l) {
        float xa = xav[l >> 2][l & 3];
        float xb = xbv[l >> 2][l & 3];
        float hm1  = dpp_shr1(h);               // h[m-1]
        float t    = is_m0 ? NEG : (hm1 + eps_r);
        float ae   = fmaxf(h, t);               // after_eps[m]
        float aem1 = dpp_shr1(ae);              // after_eps[m-1]
        float mn   = is_m0 ? 0.0f : (aem1 + xb);// main[m] (restart at m=0)
        h = fmaxf(mn, ae + xa);                 // max(main, self_loop)
        s = fmaxf(s, h);                        // only lane m==6 meaningful
    }
}

__global__ __launch_bounds__(512, 2)
void sopa_kernel(const uint16_t* __restrict__ A_ws,
                 const uint16_t* __restrict__ B_ws,
                 const float* __restrict__ epsilon,
                 float* __restrict__ scores_g)
{
    extern __shared__ char smem[];
    // LDS layout: [A buf0 | A buf1 | A buf2 | SC buf0 | SC buf1]

    const int blk = blockIdx.x;
    const int bb  = blk / NTILE;
    const int pt  = blk - bb * NTILE;
    const int d0  = pt * DT;
    const int p0  = pt * PT;

    const int tid  = threadIdx.x;
    const int wave = tid >> 6;
    const int lane = tid & 63;

    // ---- MFMA-wave geometry (waves 0-3: grid 2 rows x 2 col-groups)
    const int rlo = lane & 15;
    const int kq  = lane >> 4;
    const int wr  = wave & 1;
    const int wc  = (wave >> 1) & 1;
    const int cb  = wc * 4;                 // col-frag base: {0..3} or {4..6}
    const int arow  = wr * 16 + rlo;
    const int abase = arow * ROWB;
    const int aswz  = (arow & 7) << 4;

    // ---- B fragments -> registers, UNCONDITIONAL defs (no runtime branch in
    // the def path -> no scratch demotion). wc==1 waves load 16 junk cols
    // (rows 2800..2815 of padded B) into breg[30..39]; never fed to MFMA.
    bf16x8 breg[40];
    if (wave < 4) {
        const uint16_t* Bg = B_ws + (size_t)d0 * KP;
#pragma unroll
        for (int f = 0; f < 4; ++f) {
#pragma unroll
            for (int kk = 0; kk < 10; ++kk) {
                const int col = (cb + f) * 16 + rlo;
                const int jp  = (kk * 4 + kq) ^ (col & 7);
                breg[f * 10 + kk] = *reinterpret_cast<const bf16x8*>(
                    Bg + (size_t)col * KP + jp * 8);
                pin(breg[f * 10 + kk]);
            }
        }
    }

    // ---- scan-wave state (waves 4-5, 4 patterns each; lane = q*8+m,
    // q>=4 duplicates q-4; m==7 lanes are dummies)
    const int  q  = lane >> 3;
    const int  mm = lane & 7;
    const int  pl = ((wave == 5) ? 4 : 0) + (q & 3);   // local pattern 0..7
    const bool is_m0 = (mm == 0);
    float eps_r = 0.0f;
    if (mm >= 1 && mm <= 6) eps_r = epsilon[(p0 + pl) * 6 + (mm - 1)];
    const int i0 = pl * 14 + mm;                       // x[p][0][m]
    const int i1 = pl * 14 + 7 + (mm ? mm - 1 : 0);    // x[p][1][m-1]
    float h = is_m0 ? 0.0f : NEG;
    float s = NEG;

    // ---- stager geometry (waves 6-7): 10 KB each per chunk, linear copy
    const int   wv    = wave & 1;
    const char* a_src = (const char*)(A_ws + (size_t)bb * NL * KP) + wv * 10240 + lane * 16;

    if (wave >= 6) {
        // prologue: issue chunks 0 and 1; wait chunk0 complete (newest 10 = chunk1 ok)
#pragma unroll
        for (int i = 0; i < 10; ++i)
            gload16(a_src + i * 1024, smem + wv * 10240 + i * 1024);
#pragma unroll
        for (int i = 0; i < 10; ++i)
            gload16(a_src + LC * ROWB + i * 1024, smem + LDS_A + wv * 10240 + i * 1024);
        WAIT_VM(10);
    }
    SBAR();

    for (int c = 0; c < NCHUNK; ++c) {
        if (wave < 4) {
            const char* Ab  = smem + (c % 3) * LDS_A;
            float*      scw = (float*)(smem + 3 * LDS_A + (c & 1) * LDS_SC);
            if (wc == 0) mfma_body<4>(Ab, breg, scw, abase, aswz, cb, rlo, kq, wr);
            else         mfma_body<3>(Ab, breg, scw, abase, aswz, cb, rlo, kq, wr);
            WAIT_LGKM0();                    // SC writes visible before barrier
            SBAR();
        } else if (wave < 6) {
            if (c > 0) {
                const float* scr = (const float*)(smem + 3 * LDS_A + ((c - 1) & 1) * LDS_SC);
                scan_chunk(scr, h, s, eps_r, is_m0, i0, i1);
            }
            SBAR();
        } else {
            if (c + 2 < NCHUNK) {
                // issue chunk c+2 into buf[(c+2)%3] (read last period -> free)
                const char* src = a_src + (size_t)(c + 2) * LC * ROWB;
                char*       lb  = smem + ((c + 2) % 3) * LDS_A + wv * 10240;
#pragma unroll
                for (int i = 0; i < 10; ++i)
                    gload16(src + i * 1024, lb + i * 1024);
                WAIT_VM(10);                 // all but newest 10 done = chunk c+1 ready
            } else {
                WAIT_VM(0);                  // tail: drain (loads are a period old)
            }
            SBAR();
        }
    }

    if (wave == 4 || wave == 5) {
        const float* scr = (const float*)(smem + 3 * LDS_A + ((NCHUNK - 1) & 1) * LDS_SC);
        scan_chunk(scr, h, s, eps_r, is_m0, i0, i1);
        if (q < 4 && mm == 6) scores_g[bb * NP + p0 + pl] = s;
    }
}

// ---------------------------------------------------------------------------
// tiny MLP head: one block per batch row, fp32
// ---------------------------------------------------------------------------
__global__ void mlp_kernel(const float* __restrict__ scores_g,
                           const float* __restrict__ w1, const float* __restrict__ b1,
                           const float* __restrict__ w2, const float* __restrict__ b2,
                           const float* __restrict__ w3, const float* __restrict__ b3,
                           float* __restrict__ out)
{
    __shared__ float sc[NP];
    __shared__ float h1[NH];
    __shared__ float h2[NH];
    int b = blockIdx.x, t = threadIdx.x;
    for (int i = t; i < NP; i += blockDim.x) sc[i] = scores_g[b * NP + i];
    __syncthreads();
    if (t < NH) {
        float acc = b1[t];
#pragma unroll 8
        for (int k = 0; k < NP; ++k) acc += sc[k] * w1[k * NH + t];
        h1[t] = fmaxf(acc, 0.0f);
    }
    __syncthreads();
    if (t < NH) {
        float acc = b2[t];
#pragma unroll 8
        for (int k = 0; k < NH; ++k) acc += h1[k] * w2[k * NH + t];
        h2[t] = fmaxf(acc, 0.0f);
    }
    __syncthreads();
    if (t < 64) {
        float l0 = 0.0f, l1 = 0.0f;
        for (int k = t; k < NH; k += 64) {
            float hv = h2[k];
            l0 += hv * w3[k * 2];
            l1 += hv * w3[k * 2 + 1];
        }
#pragma unroll
        for (int off = 32; off > 0; off >>= 1) {
            l0 += __shfl_down(l0, off);
            l1 += __shfl_down(l1, off);
        }
        if (t == 0) {
            l0 += b3[0]; l1 += b3[1];
            float mx  = fmaxf(l0, l1);
            float lse = mx + logf(expf(l0 - mx) + expf(l1 - mx));
            out[b * 2 + 0] = l0 - lse;
            out[b * 2 + 1] = l1 - lse;
        }
    }
}

extern "C" void kernel_launch(void* const* d_in, const int* in_sizes, int n_in,
                              void* d_out, int out_size, void* d_ws, size_t ws_size,
                              hipStream_t stream)
{
    const int*   docs  = (const int*)  d_in[0];
    const float* emb   = (const float*)d_in[1];
    const float* diags = (const float*)d_in[2];
    const float* bias  = (const float*)d_in[3];
    const float* eps   = (const float*)d_in[4];
    const float* w1 = (const float*)d_in[5];
    const float* b1 = (const float*)d_in[6];
    const float* w2 = (const float*)d_in[7];
    const float* b2 = (const float*)d_in[8];
    const float* w3 = (const float*)d_in[9];
    const float* b3 = (const float*)d_in[10];
    float* out = (float*)d_out;

    char* ws = (char*)d_ws;
    uint16_t* A_ws     = (uint16_t*)ws;                              // 20,971,520 B
    uint16_t* B_ws     = (uint16_t*)(ws + 20971520);                 // NDP*KP*2 = 1,802,240 B
    float*    scores_g = (float*)   (ws + 20971520 + 1802240);       //     51,200 B

    {
        int totalUnits = (NB * NL + ND) * UNITS;
        int blocks = (totalUnits + 255) / 256;
        prep_kernel<<<blocks, 256, 0, stream>>>(docs, emb, diags, bias, A_ws, B_ws);
    }

    (void)hipFuncSetAttribute(reinterpret_cast<const void*>(sopa_kernel),
                              hipFuncAttributeMaxDynamicSharedMemorySize, LDS_TOTAL);
    sopa_kernel<<<NB * NTILE, 512, LDS_TOTAL, stream>>>(A_ws, B_ws, eps, scores_g);

    mlp_kernel<<<NB, 128, 0, stream>>>(scores_g, w1, b1, w2, b2, w3, b3, out);
}

// Round 7
// 264.065 us; speedup vs baseline: 1.4542x; 1.1500x over previous
//
#include <hip/hip_runtime.h>
#include <stdint.h>

#define NEG (-100.0f)

#define NE 300      // embedding dim
#define NB 64       // batch
#define NL 512      // seq len
#define NP 200      // patterns
#define NH 100      // mlp hidden

#define KP 320      // padded K (300 emb + 1 bias-col + zeros)
#define UNITS 40    // 16B units per row (KP*2/16)
#define ROWB 640    // bytes per row

#define PT 8        // patterns per tile
#define DT 112      // real diag rows per tile (PT*14)
#define DTP 128     // padded B rows per tile (4 col-groups of 32)
#define NTILE 25    // pattern tiles (200/8)
#define NBROWS (NTILE*DTP)   // 3200 padded B rows total
#define LC 32       // l-chunk
#define NCHUNK 16   // 512/32
#define SCW 36      // transposed score tile: sc[col][l], stride 36 floats

#define LDS_A   (LC*ROWB)          // 20480
#define LDS_SC  (DT*SCW*4)         // 16128
#define LDS_TOTAL (3*LDS_A + 2*LDS_SC)   // 93696

using f32x4  = __attribute__((ext_vector_type(4))) float;
using f32x16 = __attribute__((ext_vector_type(16))) float;
using bf16x8 = __attribute__((ext_vector_type(8))) __bf16;

// raw barrier (no compiler vmcnt/lgkmcnt drain) + counted waits (T3/T4)
#define SBAR()       asm volatile("s_barrier" ::: "memory")
#define WAIT_LGKM0() do { asm volatile("s_waitcnt lgkmcnt(0)" ::: "memory"); \
                          __builtin_amdgcn_sched_barrier(0); } while (0)
#define WAIT_VM(N)   do { asm volatile("s_waitcnt vmcnt(" #N ")" ::: "memory"); \
                          __builtin_amdgcn_sched_barrier(0); } while (0)

static __device__ __forceinline__ void gload16(const void* g, void* l) {
    __builtin_amdgcn_global_load_lds(
        (const __attribute__((address_space(1))) void*)g,
        (__attribute__((address_space(3))) void*)l, 16, 0, 0);
}

static __device__ __forceinline__ uint16_t f2bf(float f) {
    union { float f; uint32_t u; } v; v.f = f;
    return (uint16_t)((v.u + 0x7FFFu + ((v.u >> 16) & 1u)) >> 16);   // RNE
}

// keep-alive: forbids rematerialization/demotion of x
static __device__ __forceinline__ void pin(bf16x8& x) {
    asm volatile("" : "+v"(x));
}

// lane i gets lane i-1's value (within rows of 16); row-lane 0 gets 0.
static __device__ __forceinline__ float dpp_shr1(float x) {
    int r = __builtin_amdgcn_update_dpp(0, __float_as_int(x), 0x111, 0xF, 0xF, true);
    return __int_as_float(r);
}

// ---------------------------------------------------------------------------
// prep: gather emb rows by docs, convert to bf16, pad K to 320 (col 300 = 1.0
// for A / bias[d] for B), store 16B units PRE-SWIZZLED (unit j at j^(row&7)).
// B is laid out as [NTILE][128][KP]: tile-local rows 112..127 are zeroed
// (junk cols consumed by masked MFMA output only).
// ---------------------------------------------------------------------------
__global__ void prep_kernel(const int* __restrict__ docs,
                            const float* __restrict__ emb,
                            const float* __restrict__ diags,
                            const float* __restrict__ bias,
                            uint16_t* __restrict__ A_ws,
                            uint16_t* __restrict__ B_ws)
{
    int tid = blockIdx.x * blockDim.x + threadIdx.x;
    const int totalA = NB * NL * UNITS;
    const int total  = totalA + NBROWS * UNITS;
    if (tid >= total) return;
    const float* src = nullptr; uint16_t* dst; float extra = 0.0f; int r, j;
    bool valid = true;
    if (tid < totalA) {
        r = tid / UNITS; j = tid - r * UNITS;
        src = emb + (size_t)docs[r] * NE;
        dst = A_ws + (size_t)r * KP;
        extra = 1.0f;                       // bias column multiplier
    } else {
        int t2 = tid - totalA;
        r = t2 / UNITS; j = t2 - r * UNITS;
        dst = B_ws + (size_t)r * KP;
        int lr = r & (DTP - 1);
        if (lr < DT) {
            int dr = (r >> 7) * DT + lr;    // real diag row
            src = diags + (size_t)dr * NE;
            extra = bias[dr];
        } else {
            valid = false;                  // pad row -> zeros
        }
    }
    int jp = j ^ (r & 7);                   // pre-swizzle 16B unit
    union { uint16_t h[8]; uint4 v; } u;
    if (!valid) {
        u.v = uint4{0, 0, 0, 0};
    } else if (j < 37) {                    // e0+7 = 36*8+7 = 295 < 300
        float4 f0 = *reinterpret_cast<const float4*>(src + j * 8);
        float4 f1 = *reinterpret_cast<const float4*>(src + j * 8 + 4);
        u.h[0] = f2bf(f0.x); u.h[1] = f2bf(f0.y);
        u.h[2] = f2bf(f0.z); u.h[3] = f2bf(f0.w);
        u.h[4] = f2bf(f1.x); u.h[5] = f2bf(f1.y);
        u.h[6] = f2bf(f1.z); u.h[7] = f2bf(f1.w);
    } else if (j == 37) {                   // elems 296..299 real, 300 = extra
        float4 f0 = *reinterpret_cast<const float4*>(src + 296);
        u.h[0] = f2bf(f0.x); u.h[1] = f2bf(f0.y);
        u.h[2] = f2bf(f0.z); u.h[3] = f2bf(f0.w);
        u.h[4] = f2bf(extra); u.h[5] = 0; u.h[6] = 0; u.h[7] = 0;
    } else {                                // zero pad
        u.v = uint4{0, 0, 0, 0};
    }
    *reinterpret_cast<uint4*>(dst + (size_t)jp * 8) = u.v;
}

static __device__ __forceinline__ void scan_chunk(const float* __restrict__ sc,
        float& h, float& s, float eps_r, bool is_m0, int i0, int i1)
{
    // preload the whole chunk: xa[l] = sc[i0*SCW + l], xb[l] = sc[i1*SCW + l]
    f32x4 xav[8], xbv[8];
#pragma unroll
    for (int i = 0; i < 8; ++i)
        xav[i] = *reinterpret_cast<const f32x4*>(sc + i0 * SCW + i * 4);
#pragma unroll
    for (int i = 0; i < 8; ++i)
        xbv[i] = *reinterpret_cast<const f32x4*>(sc + i1 * SCW + i * 4);
#pragma unroll
    for (int l = 0; l < LC; ++l) {
        float xa = xav[l >> 2][l & 3];
        float xb = xbv[l >> 2][l & 3];
        float hm1  = dpp_shr1(h);               // h[m-1]
        float t    = is_m0 ? NEG : (hm1 + eps_r);
        float ae   = fmaxf(h, t);               // after_eps[m]
        float aem1 = dpp_shr1(ae);              // after_eps[m-1]
        float mn   = is_m0 ? 0.0f : (aem1 + xb);// main[m] (restart at m=0)
        h = fmaxf(mn, ae + xa);                 // max(main, self_loop)
        s = fmaxf(s, h);                        // only lane m==6 meaningful
    }
}

// ---------------------------------------------------------------------------
// fused GEMM (bf16 MFMA 32x32x16, B resident: breg[20] = 80 VGPR/wave) +
// max-plus scan. 8 waves: 0-3 MFMA (one 32-col group each), 4-5 scan,
// 6-7 stagers (global_load_lds 2 chunks ahead, A triple-buffered,
// counted vmcnt across raw s_barrier).
// ---------------------------------------------------------------------------
__global__ __launch_bounds__(512) __attribute__((amdgpu_waves_per_eu(2, 2)))
void sopa_kernel(const uint16_t* __restrict__ A_ws,
                 const uint16_t* __restrict__ B_ws,
                 const float* __restrict__ epsilon,
                 float* __restrict__ scores_g)
{
    extern __shared__ char smem[];
    // LDS layout: [A buf0 | A buf1 | A buf2 | SC buf0 | SC buf1]

    const int blk = blockIdx.x;
    const int bb  = blk / NTILE;
    const int pt  = blk - bb * NTILE;
    const int p0  = pt * PT;

    const int tid  = threadIdx.x;
    const int wave = tid >> 6;
    const int lane = tid & 63;

    if (wave < 4) {
        // ---------------- MFMA persona ----------------
        const int arow  = lane & 31;        // A row within chunk / output l
        const int khalf = lane >> 5;        // k-halves of 16-wide K step
        const int col   = wave * 32 + arow; // output diag-row (padded to 128)
        const int abase = arow * ROWB;
        const int ax3   = arow & 7;
        const bool wr_ok = col < DT;

        // B fragments -> registers, once. 20 frags = 80 VGPR.
        bf16x8 breg[20];
        const uint16_t* Bg = B_ws + ((size_t)pt * DTP + col) * KP;
#pragma unroll
        for (int st = 0; st < 20; ++st) {
            int jp = (st * 2 + khalf) ^ (col & 7);
            breg[st] = *reinterpret_cast<const bf16x8*>(Bg + jp * 8);
            pin(breg[st]);
        }
        SBAR();

        for (int c = 0; c < NCHUNK; ++c) {
            const char* Ab  = smem + (c % 3) * LDS_A;
            float*      scw = (float*)(smem + 3 * LDS_A + (c & 1) * LDS_SC);
            f32x16 acc;
#pragma unroll
            for (int i = 0; i < 16; ++i) acc[i] = 0.0f;
#pragma unroll
            for (int st = 0; st < 20; ++st) {
                int jx = (st * 2 + khalf) ^ ax3;
                bf16x8 av = *reinterpret_cast<const bf16x8*>(Ab + abase + jx * 16);
                acc = __builtin_amdgcn_mfma_f32_32x32x16_bf16(av, breg[st], acc, 0, 0, 0);
            }
            // C/D: col = lane&31, row = (reg&3) + 8*(reg>>2) + 4*khalf
            if (wr_ok) {
#pragma unroll
                for (int g = 0; g < 4; ++g) {
                    f32x4 v;
                    v[0] = acc[g * 4 + 0]; v[1] = acc[g * 4 + 1];
                    v[2] = acc[g * 4 + 2]; v[3] = acc[g * 4 + 3];
                    *reinterpret_cast<f32x4*>(scw + col * SCW + g * 8 + khalf * 4) = v;
                }
            }
            WAIT_LGKM0();                    // SC writes visible before barrier
            SBAR();
        }
    } else if (wave < 6) {
        // ---------------- scan persona (4 patterns each) ----------------
        const int  q  = lane >> 3;
        const int  mm = lane & 7;
        const int  pl = ((wave == 5) ? 4 : 0) + (q & 3);   // local pattern 0..7
        const bool is_m0 = (mm == 0);
        float eps_r = 0.0f;
        if (mm >= 1 && mm <= 6) eps_r = epsilon[(p0 + pl) * 6 + (mm - 1)];
        const int i0 = pl * 14 + mm;                       // x[p][0][m]
        const int i1 = pl * 14 + 7 + (mm ? mm - 1 : 0);    // x[p][1][m-1]
        float h = is_m0 ? 0.0f : NEG;
        float s = NEG;

        SBAR();
        for (int c = 0; c < NCHUNK; ++c) {
            if (c > 0) {
                const float* scr = (const float*)(smem + 3 * LDS_A + ((c - 1) & 1) * LDS_SC);
                scan_chunk(scr, h, s, eps_r, is_m0, i0, i1);
            }
            SBAR();
        }
        const float* scr = (const float*)(smem + 3 * LDS_A + ((NCHUNK - 1) & 1) * LDS_SC);
        scan_chunk(scr, h, s, eps_r, is_m0, i0, i1);
        if (q < 4 && mm == 6) scores_g[bb * NP + p0 + pl] = s;
    } else {
        // ---------------- stager persona ----------------
        const int   wv    = wave & 1;
        const char* a_src = (const char*)(A_ws + (size_t)bb * NL * KP) + wv * 10240 + lane * 16;

        // prologue: issue chunks 0 and 1; wait chunk0 complete
#pragma unroll
        for (int i = 0; i < 10; ++i)
            gload16(a_src + i * 1024, smem + wv * 10240 + i * 1024);
#pragma unroll
        for (int i = 0; i < 10; ++i)
            gload16(a_src + LC * ROWB + i * 1024, smem + LDS_A + wv * 10240 + i * 1024);
        WAIT_VM(10);
        SBAR();

        for (int c = 0; c < NCHUNK; ++c) {
            if (c + 2 < NCHUNK) {
                // issue chunk c+2 into buf[(c+2)%3] (read last period -> free)
                const char* src = a_src + (size_t)(c + 2) * LC * ROWB;
                char*       lb  = smem + ((c + 2) % 3) * LDS_A + wv * 10240;
#pragma unroll
                for (int i = 0; i < 10; ++i)
                    gload16(src + i * 1024, lb + i * 1024);
                WAIT_VM(10);                 // all but newest 10 done = chunk c+1 ready
            } else {
                WAIT_VM(0);                  // tail: drain (loads are a period old)
            }
            SBAR();
        }
    }
}

// ---------------------------------------------------------------------------
// tiny MLP head: one block per batch row, fp32
// ---------------------------------------------------------------------------
__global__ void mlp_kernel(const float* __restrict__ scores_g,
                           const float* __restrict__ w1, const float* __restrict__ b1,
                           const float* __restrict__ w2, const float* __restrict__ b2,
                           const float* __restrict__ w3, const float* __restrict__ b3,
                           float* __restrict__ out)
{
    __shared__ float sc[NP];
    __shared__ float h1[NH];
    __shared__ float h2[NH];
    int b = blockIdx.x, t = threadIdx.x;
    for (int i = t; i < NP; i += blockDim.x) sc[i] = scores_g[b * NP + i];
    __syncthreads();
    if (t < NH) {
        float acc = b1[t];
#pragma unroll 8
        for (int k = 0; k < NP; ++k) acc += sc[k] * w1[k * NH + t];
        h1[t] = fmaxf(acc, 0.0f);
    }
    __syncthreads();
    if (t < NH) {
        float acc = b2[t];
#pragma unroll 8
        for (int k = 0; k < NH; ++k) acc += h1[k] * w2[k * NH + t];
        h2[t] = fmaxf(acc, 0.0f);
    }
    __syncthreads();
    if (t < 64) {
        float l0 = 0.0f, l1 = 0.0f;
        for (int k = t; k < NH; k += 64) {
            float hv = h2[k];
            l0 += hv * w3[k * 2];
            l1 += hv * w3[k * 2 + 1];
        }
#pragma unroll
        for (int off = 32; off > 0; off >>= 1) {
            l0 += __shfl_down(l0, off);
            l1 += __shfl_down(l1, off);
        }
        if (t == 0) {
            l0 += b3[0]; l1 += b3[1];
            float mx  = fmaxf(l0, l1);
            float lse = mx + logf(expf(l0 - mx) + expf(l1 - mx));
            out[b * 2 + 0] = l0 - lse;
            out[b * 2 + 1] = l1 - lse;
        }
    }
}

extern "C" void kernel_launch(void* const* d_in, const int* in_sizes, int n_in,
                              void* d_out, int out_size, void* d_ws, size_t ws_size,
                              hipStream_t stream)
{
    const int*   docs  = (const int*)  d_in[0];
    const float* emb   = (const float*)d_in[1];
    const float* diags = (const float*)d_in[2];
    const float* bias  = (const float*)d_in[3];
    const float* eps   = (const float*)d_in[4];
    const float* w1 = (const float*)d_in[5];
    const float* b1 = (const float*)d_in[6];
    const float* w2 = (const float*)d_in[7];
    const float* b2 = (const float*)d_in[8];
    const float* w3 = (const float*)d_in[9];
    const float* b3 = (const float*)d_in[10];
    float* out = (float*)d_out;

    char* ws = (char*)d_ws;
    uint16_t* A_ws     = (uint16_t*)ws;                              // 20,971,520 B
    uint16_t* B_ws     = (uint16_t*)(ws + 20971520);                 // NBROWS*KP*2 = 2,048,000 B
    float*    scores_g = (float*)   (ws + 20971520 + 2048000);       //     51,200 B

    {
        int totalUnits = (NB * NL + NBROWS) * UNITS;
        int blocks = (totalUnits + 255) / 256;
        prep_kernel<<<blocks, 256, 0, stream>>>(docs, emb, diags, bias, A_ws, B_ws);
    }

    (void)hipFuncSetAttribute(reinterpret_cast<const void*>(sopa_kernel),
                              hipFuncAttributeMaxDynamicSharedMemorySize, LDS_TOTAL);
    sopa_kernel<<<NB * NTILE, 512, LDS_TOTAL, stream>>>(A_ws, B_ws, eps, scores_g);

    mlp_kernel<<<NB, 128, 0, stream>>>(scores_g, w1, b1, w2, b2, w3, b3, out);
}